// Round 8
// baseline (78.223 us; speedup 1.0000x reference)
//
#include <hip/hip_runtime.h>

#define BB 8
#define HH 256
#define WW 256
#define NTOT (BB * HH * WW)   // 524288
#define RPB 8                 // rows per block
#define NBLK (BB * HH / RPB)  // 256 blocks = 1 per CU

// ------- Kernel 1 (mega): window mask + outward walk vertical EDT +
//         pruned exact horizontal min + fused elementwise + reduce ---------
// Block = RPB consecutive rows of one image. Vertical distance per column:
// exact nearest foreground via 8-row window mask + outward coalesced row
// walks with per-wave early exit. Columns with window bit at the walk-side
// edge (bit0 up / bit7 down) are pre-resolved: the edge row beats any
// outside row. Unresolved columns walk to the image boundary -> exact.
// Pruning exactness: k=j gives dt2(j) <= g2(j) so argmin |j-k*| <= d_j;
// R = block_max(min(d,255)) >= every row's own max -> exact scan radius.
__global__ __launch_bounds__(256) void mega_kernel(
    const float* __restrict__ logits, const float* __restrict__ target,
    float* __restrict__ partials /* [5][NBLK] */) {
  __shared__ float s_g2[RPB][3 * WW];  // [pad | row | pad]
  __shared__ float s_red[4 * 5];
  __shared__ int s_im[4 * 2];  // per-wave {any, rmax}

  const int g = blockIdx.x;        // 0..255
  const int b = g >> 5;            // 32 blocks per image
  const int i0 = (g & 31) * RPB;   // first row within image
  const int j = threadIdx.x;       // column
  const int lane = j & 63, wave = j >> 6;

  const float* img = target + b * (HH * WW);

  // own-window 8-bit column mask (8 coalesced row loads)
  unsigned m8 = 0;
#pragma unroll
  for (int r = 0; r < RPB; ++r)
    if (img[(i0 + r) * WW + j] > 0.5f) m8 |= (1u << r);

  // walk up (rows i0-1-k). Pre-resolved if bit0 set.
  const int INFD = 1 << 24;
  int kUp = INFD;
  bool fUp = (m8 & 1u) != 0u;
  bool sawUp = false;
  for (int k0 = 0; k0 < i0 && !__all(fUp); k0 += 8) {
    bool fgv[8];
#pragma unroll
    for (int kk = 0; kk < 8; ++kk) {
      const int k = k0 + kk;
      fgv[kk] = (k < i0) && (img[(i0 - 1 - k) * WW + j] > 0.5f);
    }
#pragma unroll
    for (int kk = 0; kk < 8; ++kk)
      if (!fUp && fgv[kk]) { kUp = k0 + kk; fUp = true; sawUp = true; }
  }

  // walk down (rows i0+RPB+k). Pre-resolved if bit RPB-1 set.
  const int limDn = HH - i0 - RPB;
  int kDn = INFD;
  bool fDn = (m8 >> (RPB - 1)) & 1u;
  bool sawDn = false;
  for (int k0 = 0; k0 < limDn && !__all(fDn); k0 += 8) {
    bool fgv[8];
#pragma unroll
    for (int kk = 0; kk < 8; ++kk) {
      const int k = k0 + kk;
      fgv[kk] = (k < limDn) && (img[(i0 + RPB + k) * WW + j] > 0.5f);
    }
#pragma unroll
    for (int kk = 0; kk < 8; ++kk)
      if (!fDn && fgv[kk]) { kDn = k0 + kk; fDn = true; sawDn = true; }
  }

  // vertical distances for the 8 rows; sentinel pads; scan radius
  int rmax = 0;
#pragma unroll
  for (int r = 0; r < RPB; ++r) {
    // nearest at row' >= i: window bits >= r, else walk-down
    const unsigned hi = m8 >> r;
    const int dA = hi ? __builtin_ctz(hi) : (RPB - r + kDn);
    // nearest at row' <= i: window bits <= r, else walk-up
    const unsigned lo = m8 & ((1u << (r + 1)) - 1u);
    const int dB = lo ? (r - (31 - __builtin_clz(lo))) : (r + 1 + kUp);
    const int d = min(dA, dB);
    s_g2[r][WW + j] = (d < 256) ? (float)(d * d) : 1.0e9f;
    s_g2[r][j] = 1.0e9f;           // left pad
    s_g2[r][2 * WW + j] = 1.0e9f;  // right pad
    rmax = max(rmax, min(d, 255));
  }

  const int wave_any = __any((m8 != 0u) | sawUp | sawDn);
#pragma unroll
  for (int off = 32; off > 0; off >>= 1)
    rmax = max(rmax, __shfl_down(rmax, off, 64));
  if (lane == 0) { s_im[wave * 2] = wave_any; s_im[wave * 2 + 1] = rmax; }
  __syncthreads();
  const int nonempty = s_im[0] | s_im[2] | s_im[4] | s_im[6];
  const int R = max(max(s_im[1], s_im[3]), max(s_im[5], s_im[7]));

  // per-row pruned horizontal min + fused elementwise
  float v0 = 0.f, v1 = 0.f, v2 = 0.f, v3 = 0.f, v4 = 0.f;
#pragma unroll
  for (int r = 0; r < RPB; ++r) {
    float mn = 1.0e30f;
    const float* gp = &s_g2[r][WW + j];
    for (int dlt = -R; dlt <= R; ++dlt)
      mn = fminf(mn, (float)(dlt * dlt) + gp[dlt]);
    const float dt = nonempty ? sqrtf(mn) : 0.0f;

    const int idx = (b * HH + i0 + r) * WW + j;
    const float x = logits[idx];
    float t = img[(i0 + r) * WW + j];  // L1-resident reload
    t = fminf(fmaxf(t, 0.0f), 1.0f);
    const float e = __expf(-fabsf(x));
    const float inv = 1.0f / (1.0f + e);
    const float ce = fmaxf(x, 0.0f) + __logf(1.0f + e) - x * t;
    float p = (x >= 0.0f) ? inv : e * inv;  // sigmoid
    p = fminf(fmaxf(p, 1e-6f), 1.0f - 1e-6f);
    v0 += ce; v1 += p; v2 += t; v3 += p * t; v4 += p * dt;
  }

  // block reduce (fp32) -> per-block partial stores
  float v[5] = {v0, v1, v2, v3, v4};
#pragma unroll
  for (int q = 0; q < 5; ++q) {
    float s = v[q];
#pragma unroll
    for (int off = 32; off > 0; off >>= 1) s += __shfl_down(s, off, 64);
    if (lane == 0) s_red[wave * 5 + q] = s;
  }
  __syncthreads();
  if (j == 0) {
#pragma unroll
    for (int q = 0; q < 5; ++q)
      partials[q * NBLK + g] =
          s_red[q] + s_red[5 + q] + s_red[10 + q] + s_red[15 + q];
  }
}

// ---------------- Kernel 2: final reduction (double) + loss math -----------
__global__ __launch_bounds__(256) void finalize(
    const float* __restrict__ partials, float* __restrict__ out) {
  __shared__ double s_red[4 * 5];
  const int j = threadIdx.x;  // 256 threads, one partial each
  const int lane = j & 63, wave = j >> 6;
  double acc[5];
#pragma unroll
  for (int q = 0; q < 5; ++q) acc[q] = (double)partials[q * NBLK + j];
#pragma unroll
  for (int q = 0; q < 5; ++q) {
    double s = acc[q];
#pragma unroll
    for (int off = 32; off > 0; off >>= 1) s += __shfl_down(s, off, 64);
    if (lane == 0) s_red[wave * 5 + q] = s;
  }
  __syncthreads();
  if (j == 0) {
    double sum[5];
#pragma unroll
    for (int q = 0; q < 5; ++q)
      sum[q] = s_red[q] + s_red[5 + q] + s_red[10 + q] + s_red[15 + q];
    const double n = (double)NTOT;
    const double ce = sum[0] / n;
    const double dice = 1.0 - (2.0 * sum[3] + 1e-6) / (sum[1] + sum[2] + 1e-6);
    const double boundary = sum[4] / n;
    out[0] = (float)(ce + dice + 0.1 * boundary);
    out[1] = (float)ce;
    out[2] = (float)dice;
    out[3] = (float)boundary;
  }
}

extern "C" void kernel_launch(void* const* d_in, const int* in_sizes, int n_in,
                              void* d_out, int out_size, void* d_ws,
                              size_t ws_size, hipStream_t stream) {
  const float* logits = (const float*)d_in[0];
  const float* target = (const float*)d_in[1];
  float* out = (float*)d_out;

  float* partials = (float*)d_ws;  // 5*256*4 = 5 KB

  mega_kernel<<<NBLK, 256, 0, stream>>>(logits, target, partials);
  finalize<<<1, 256, 0, stream>>>(partials, out);
}

// Round 9
// 65.477 us; speedup vs baseline: 1.1947x; 1.1947x over previous
//
#include <hip/hip_runtime.h>

#define BB 8
#define HH 256
#define WW 256
#define NTOT (BB * HH * WW)   // 524288
#define RPB 4                 // rows per block in main kernel
#define NBLK (BB * HH / RPB)  // 512

// ---------------- Kernel 1: per-column foreground bitmasks -----------------
__global__ __launch_bounds__(256) void build_masks(
    const float* __restrict__ target, unsigned* __restrict__ masks) {
  const int s = blockIdx.x;  // stripe 0..7 (rows 32s..32s+31)
  const int b = blockIdx.y;  // batch 0..7
  const int j = threadIdx.x; // column
  const float* base = target + b * (HH * WW) + s * 32 * WW + j;
  unsigned m = 0;
#pragma unroll
  for (int r = 0; r < 32; ++r)
    if (base[r * WW] > 0.5f) m |= (1u << r);
  masks[b * 2048 + s * 256 + j] = m;
}

// ------- Kernel 2: vertical EDT + pruned exact horizontal min + fused ------
// Block = RPB consecutive rows of one image. Pruning exactness: k=j gives
// dt2(j) <= g2(j), so any argmin k* has |j-k*| <= d_j; scanning
// |delta| <= R with R = block_max over all RPB rows of min(d,255) is >=
// each row's own max -> exact. s_g2 rows carry sentinel margins so the
// scan needs no bounds check; +/-delta handled pairwise per iteration.
__global__ __launch_bounds__(256) void main_kernel(
    const float* __restrict__ logits, const float* __restrict__ target,
    const unsigned* __restrict__ masks,
    float* __restrict__ partials /* [5][NBLK] */) {
  __shared__ float s_g2[RPB][3 * WW];  // [pad | row | pad], sentinel-filled
  __shared__ float s_red[4 * 5];
  __shared__ int s_im[4 * 2];  // per-wave {any, rmax}

  const int g = blockIdx.x;        // 0..511
  const int b = g >> 6;            // 64 blocks per image
  const int i0 = (g & 63) * RPB;   // first row within image
  const int j = threadIdx.x;
  const int lane = j & 63, wave = j >> 6;

  // column masks (whole image column, 256 bits)
  unsigned m[8];
#pragma unroll
  for (int w = 0; w < 8; ++w) m[w] = masks[b * 2048 + w * 256 + j];
  const unsigned many = m[0] | m[1] | m[2] | m[3] | m[4] | m[5] | m[6] | m[7];

  // vertical distances for RPB rows; sentinel pads; track scan radius
  int rmax = 0;
#pragma unroll
  for (int r = 0; r < RPB; ++r) {
    const int i = i0 + r;
    const int wi = i >> 5, rr = i & 31;
    int dUp = 1 << 30, dDn = 1 << 30;
    const unsigned cur = m[wi] >> rr;  // bits at rows >= i
    if (cur) {
      dUp = __builtin_ctz(cur);
    } else {
      int off = 32 - rr;
      for (int w2 = wi + 1; w2 < 8; ++w2, off += 32)
        if (m[w2]) { dUp = off + __builtin_ctz(m[w2]); break; }
    }
    const unsigned curd = m[wi] << (31 - rr);  // bits at rows <= i
    if (curd) {
      dDn = __builtin_clz(curd);
    } else {
      int off = rr + 1;
      for (int w2 = wi - 1; w2 >= 0; --w2, off += 32)
        if (m[w2]) { dDn = off + __builtin_clz(m[w2]); break; }
    }
    const int d = min(dUp, dDn);
    s_g2[r][WW + j] = (d < 256) ? (float)(d * d) : 1.0e9f;
    s_g2[r][j] = 1.0e9f;           // left pad
    s_g2[r][2 * WW + j] = 1.0e9f;  // right pad
    rmax = max(rmax, min(d, 255));
  }

  const int wave_any = __any(many != 0u);
#pragma unroll
  for (int off = 32; off > 0; off >>= 1)
    rmax = max(rmax, __shfl_down(rmax, off, 64));
  if (lane == 0) { s_im[wave * 2] = wave_any; s_im[wave * 2 + 1] = rmax; }
  __syncthreads();
  const int nonempty = s_im[0] | s_im[2] | s_im[4] | s_im[6];
  const int R = max(max(s_im[1], s_im[3]), max(s_im[5], s_im[7]));

  // per-row pruned horizontal min + fused elementwise, accumulated locally
  float v0 = 0.f, v1 = 0.f, v2 = 0.f, v3 = 0.f, v4 = 0.f;
#pragma unroll
  for (int r = 0; r < RPB; ++r) {
    const float* gp = &s_g2[r][WW + j];
    float mn = gp[0];
    for (int dlt = 1; dlt <= R; ++dlt) {
      const float d2 = (float)(dlt * dlt);
      mn = fminf(mn, fminf(d2 + gp[dlt], d2 + gp[-dlt]));
    }
    const float dt = nonempty ? sqrtf(mn) : 0.0f;

    const int idx = (b * HH + i0 + r) * WW + j;
    const float x = logits[idx];
    float t = target[idx];
    t = fminf(fmaxf(t, 0.0f), 1.0f);
    const float e = __expf(-fabsf(x));
    const float inv = 1.0f / (1.0f + e);
    const float ce = fmaxf(x, 0.0f) + __logf(1.0f + e) - x * t;
    float p = (x >= 0.0f) ? inv : e * inv;  // sigmoid
    p = fminf(fmaxf(p, 1e-6f), 1.0f - 1e-6f);
    v0 += ce; v1 += p; v2 += t; v3 += p * t; v4 += p * dt;
  }

  // block reduce (fp32) -> plain per-block partial stores
  float v[5] = {v0, v1, v2, v3, v4};
#pragma unroll
  for (int q = 0; q < 5; ++q) {
    float s = v[q];
#pragma unroll
    for (int off = 32; off > 0; off >>= 1) s += __shfl_down(s, off, 64);
    if (lane == 0) s_red[wave * 5 + q] = s;
  }
  __syncthreads();
  if (j == 0) {
#pragma unroll
    for (int q = 0; q < 5; ++q)
      partials[q * NBLK + g] =
          s_red[q] + s_red[5 + q] + s_red[10 + q] + s_red[15 + q];
  }
}

// ---------------- Kernel 3: final reduction (double) + loss math -----------
__global__ __launch_bounds__(256) void finalize(
    const float* __restrict__ partials, float* __restrict__ out) {
  __shared__ double s_red[4 * 5];
  const int j = threadIdx.x;  // 256 threads
  const int lane = j & 63, wave = j >> 6;
  double acc[5];
#pragma unroll
  for (int q = 0; q < 5; ++q)
    acc[q] = (double)partials[q * NBLK + j] +
             (double)partials[q * NBLK + 256 + j];
#pragma unroll
  for (int q = 0; q < 5; ++q) {
    double s = acc[q];
#pragma unroll
    for (int off = 32; off > 0; off >>= 1) s += __shfl_down(s, off, 64);
    if (lane == 0) s_red[wave * 5 + q] = s;
  }
  __syncthreads();
  if (j == 0) {
    double sum[5];
#pragma unroll
    for (int q = 0; q < 5; ++q)
      sum[q] = s_red[q] + s_red[5 + q] + s_red[10 + q] + s_red[15 + q];
    const double n = (double)NTOT;
    const double ce = sum[0] / n;
    const double dice = 1.0 - (2.0 * sum[3] + 1e-6) / (sum[1] + sum[2] + 1e-6);
    const double boundary = sum[4] / n;
    out[0] = (float)(ce + dice + 0.1 * boundary);
    out[1] = (float)ce;
    out[2] = (float)dice;
    out[3] = (float)boundary;
  }
}

extern "C" void kernel_launch(void* const* d_in, const int* in_sizes, int n_in,
                              void* d_out, int out_size, void* d_ws,
                              size_t ws_size, hipStream_t stream) {
  const float* logits = (const float*)d_in[0];
  const float* target = (const float*)d_in[1];
  float* out = (float*)d_out;

  char* ws = (char*)d_ws;
  unsigned* masks = (unsigned*)ws;              // 8*2048*4 = 64 KB
  float* partials = (float*)(ws + 64 * 1024);   // 5*512*4 = 10 KB

  build_masks<<<dim3(8, 8), 256, 0, stream>>>(target, masks);
  main_kernel<<<NBLK, 256, 0, stream>>>(logits, target, masks, partials);
  finalize<<<1, 256, 0, stream>>>(partials, out);
}